// Round 9
// baseline (311.893 us; speedup 1.0000x reference)
//
#include <hip/hip_runtime.h>
#include <math.h>

// Problem constants (B=1 fixed by reference)
#define NP 9216          // S*S spatial positions
#define DC 256           // channels
#define DN (DC * NP)
#define NT 72            // 9216 / 128 tiles per dim
#define KCH (NP * 32)    // halves per k-chunk section of a plane

#define FEPS 2.220446049250313e-16f

typedef __attribute__((ext_vector_type(8))) _Float16 half8v;
typedef __attribute__((ext_vector_type(4))) float   float4v;

union HU { _Float16 h; unsigned short u; };
__device__ __forceinline__ unsigned short f2h(float f) { HU x; x.h = (_Float16)f; return x.u; }
__device__ __forceinline__ float h2f(unsigned short s) { HU x; x.u = s; return (float)x.h; }

// Plane layout (k-major): half index off(n,k) = (k>>5)*KCH + n*32 + (k&31)
// -> one MFMA fragment load (16 positions x 64B) is 1KB contiguous,
// perfectly coalesced global_load_dwordx4 straight from L2. ksim runs with
// no LDS staging and no barriers in the K-loop.

// ---------------- Kernel 1: fused normalize + fp16 split ----------------
// Split: H = fp16(v*2^8); L = fp16((v*2^8 - H)*2^11) (exact residual).
__global__ __launch_bounds__(256) void kprep(
    const float* __restrict__ X, const float* __restrict__ Y,
    float* __restrict__ Xf_out,
    unsigned short* __restrict__ XH, unsigned short* __restrict__ XL,
    unsigned short* __restrict__ YH, unsigned short* __restrict__ YL,
    float* __restrict__ lacc)
{
    __shared__ float tile[64 * 257];   // (n, d) at n*257+d
    __shared__ float psum[4][64];
    __shared__ float invs[64];

    const int t = threadIdx.x;
    const bool isX = (blockIdx.y == 0);
    const float* src = isX ? X : Y;
    unsigned* hT = (unsigned*)(isX ? XH : YH);
    unsigned* lT = (unsigned*)(isX ? XL : YL);
    const int n0 = blockIdx.x * 64;

    if (blockIdx.x == 0 && blockIdx.y == 0 && t == 0) *lacc = 0.0f;

    const int lane = t & 63;
    const int w    = t >> 6;      // wave id -> owns d-range [w*64, w*64+64)

    #pragma unroll 8
    for (int i = 0; i < 64; ++i) {
        int d = w * 64 + i;
        tile[lane * 257 + d] = src[(size_t)d * NP + n0 + lane];
    }
    float s = 0.0f;
    #pragma unroll 8
    for (int i = 0; i < 64; ++i) {
        float v = tile[lane * 257 + w * 64 + i];
        s = fmaf(v, v, s);
    }
    psum[w][lane] = s;
    __syncthreads();
    if (t < 64) {
        float tot = psum[0][t] + psum[1][t] + psum[2][t] + psum[3][t];
        invs[t] = 1.0f / (sqrtf(tot) + FEPS);
    }
    __syncthreads();

    // plane writes, k-major layout; coalesced uints.
    for (int kt = 0; kt < 8; ++kt) {
        #pragma unroll
        for (int p = 0; p < 4; ++p) {
            int idx = p * 256 + t;
            int n = idx >> 4;          // 0..63
            int u = idx & 15;          // uint within chunk (2 halves)
            float inv = invs[n];
            int d = kt * 32 + 2 * u;
            float v0 = tile[n * 257 + d] * inv;
            float v1 = tile[n * 257 + d + 1] * inv;
            float s0 = v0 * 256.0f, s1 = v1 * 256.0f;
            unsigned short h0 = f2h(s0), h1 = f2h(s1);
            unsigned short l0 = f2h((s0 - h2f(h0)) * 2048.0f);
            unsigned short l1 = f2h((s1 - h2f(h1)) * 2048.0f);
            size_t uo = (size_t)kt * (NP * 16) + (size_t)(n0 + n) * 16 + u;
            hT[uo] = (unsigned)h0 | ((unsigned)h1 << 16);
            lT[uo] = (unsigned)l0 | ((unsigned)l1 << 16);
        }
    }

    // exact fp32 Xf output ([d][n], coalesced over n)
    if (isX) {
        const float inv = invs[lane];
        #pragma unroll 8
        for (int i = 0; i < 64; ++i) {
            int d = w * 64 + i;
            Xf_out[(size_t)d * NP + n0 + lane] = tile[lane * 257 + d] * inv;
        }
    }
}

// ---------------- Kernel 2: MFMA sim-GEMM + fused per-row argmax ----------
// Barrier-free K-loop, fragments direct from global (k-major layout).
// R9: explicit register software-pipeline — A double-buffered at kt
// granularity, B depth-1 prefetched at cb granularity, so every load has
// >=12 MFMAs of issue-shadow (R8 exposed full L2 latency per kt: compiler
// kept zero prefetch at VGPR 76). launch_bounds(256,2): ~170 VGPR budget,
// no spill possible. sim*2^16 = Hx·Hy + 2^-11(Hx·Ly + Lx·Hy).
__global__ __launch_bounds__(256, 2) void ksim(
    const unsigned short* __restrict__ XH, const unsigned short* __restrict__ XL,
    const unsigned short* __restrict__ YH, const unsigned short* __restrict__ YL,
    float* __restrict__ pmax, int* __restrict__ pidx)
{
    __shared__ float v2s[256];
    __shared__ int   i2s[256];

    const int t  = threadIdx.x;
    const int n0 = blockIdx.x * 128;
    const int m0 = blockIdx.y * 128;

    const int L   = t & 63;
    const int wid = t >> 6;
    const int wnb = (wid >> 1) * 64;   // wave n-offset
    const int wmb = (wid & 1) * 64;    // wave m-offset (col half)
    const int lc  = L & 15;
    const int lq  = L >> 4;

    // fragment base pointers (halves); rb/cb via inst offsets (<=13-bit imm)
    const unsigned short* pAh = XH + (size_t)(n0 + wnb + lc) * 32 + lq * 8;
    const unsigned short* pAl = XL + (size_t)(n0 + wnb + lc) * 32 + lq * 8;
    const unsigned short* pBh = YH + (size_t)(m0 + wmb + lc) * 32 + lq * 8;
    const unsigned short* pBl = YL + (size_t)(m0 + wmb + lc) * 32 + lq * 8;

    float4v acc[4][4];
    #pragma unroll
    for (int i = 0; i < 4; ++i)
        #pragma unroll
        for (int j = 0; j < 4; ++j)
            acc[i][j] = (float4v){0.f, 0.f, 0.f, 0.f};
    const float4v z4 = (float4v){0.f, 0.f, 0.f, 0.f};
    const float CS = 1.0f / 2048.0f;

    half8v Ah[2][4], Al[2][4];
    half8v Bh, Bl, nBh, nBl;

    // prologue: A for kt=0 into buf0; B for (kt=0, cb=0)
    #pragma unroll
    for (int i = 0; i < 4; ++i) {
        Ah[0][i] = *(const half8v*)(pAh + i * 512);
        Al[0][i] = *(const half8v*)(pAl + i * 512);
    }
    Bh = *(const half8v*)(pBh);
    Bl = *(const half8v*)(pBl);

    // kt unrolled x2 so the A buffer index (kt&1) is compile-time.
    // Out-of-range prefetches at kt=7 land in the adjacent ws arrays
    // (valid memory, values never used).
    #pragma unroll 2
    for (int kt = 0; kt < 8; ++kt) {
        const int cur = kt & 1;
        // prefetch next kt's A fragments into the other buffer
        #pragma unroll
        for (int i = 0; i < 4; ++i) {
            Ah[cur ^ 1][i] = *(const half8v*)(pAh + KCH + i * 512);
            Al[cur ^ 1][i] = *(const half8v*)(pAl + KCH + i * 512);
        }
        #pragma unroll
        for (int cb = 0; cb < 4; ++cb) {
            // depth-1 B prefetch: next cb, or next kt's cb=0
            const unsigned short* nbh = (cb < 3) ? (pBh + (cb + 1) * 512) : (pBh + KCH);
            const unsigned short* nbl = (cb < 3) ? (pBl + (cb + 1) * 512) : (pBl + KCH);
            nBh = *(const half8v*)nbh;
            nBl = *(const half8v*)nbl;

            #pragma unroll
            for (int rb = 0; rb < 4; ++rb) {
                float4v tv;
                tv = __builtin_amdgcn_mfma_f32_16x16x32_f16(Al[cur][rb], Bh, z4, 0, 0, 0);
                tv = __builtin_amdgcn_mfma_f32_16x16x32_f16(Ah[cur][rb], Bl, tv, 0, 0, 0);
                acc[rb][cb] = __builtin_amdgcn_mfma_f32_16x16x32_f16(Ah[cur][rb], Bh, acc[rb][cb], 0, 0, 0);
                acc[rb][cb].x = fmaf(tv.x, CS, acc[rb][cb].x);
                acc[rb][cb].y = fmaf(tv.y, CS, acc[rb][cb].y);
                acc[rb][cb].z = fmaf(tv.z, CS, acc[rb][cb].z);
                acc[rb][cb].w = fmaf(tv.w, CS, acc[rb][cb].w);
            }
            Bh = nBh; Bl = nBl;
        }
        pAh += KCH; pAl += KCH; pBh += KCH; pBl += KCH;
    }

    // ---- epilogue: per-row argmax over own col-half ----
    // C/D map: col=lane&15, row=lq*4+reg. Scale 2^16 is argmax-invariant.
    float bv[16]; int bc[16];
    #pragma unroll
    for (int s = 0; s < 16; ++s) { bv[s] = -INFINITY; bc[s] = 0; }

    #pragma unroll
    for (int rb = 0; rb < 4; ++rb)
        #pragma unroll
        for (int cb = 0; cb < 4; ++cb) {   // cb ascending = col ascending
            const int col = m0 + wmb + cb * 16 + lc;
            #pragma unroll
            for (int r = 0; r < 4; ++r) {
                float v = acc[rb][cb][r];
                int s = rb * 4 + r;
                if (v > bv[s]) { bv[s] = v; bc[s] = col; }
            }
        }

    // reduce across the 16 lc lanes (xor<16 stays in the quad-group)
    #pragma unroll
    for (int off = 1; off < 16; off <<= 1) {
        #pragma unroll
        for (int s = 0; s < 16; ++s) {
            float ov = __shfl_xor(bv[s], off, 64);
            int   oi = __shfl_xor(bc[s], off, 64);
            if (ov > bv[s] || (ov == bv[s] && oi < bc[s])) { bv[s] = ov; bc[s] = oi; }
        }
    }

    // combine the two column-halves via LDS -> one slot per tile.
    // half0 cols < half1 cols: strict '>' keeps half0 on ties (first-max).
    if (lc == 0) {
        const int half = wid & 1;
        #pragma unroll
        for (int rb = 0; rb < 4; ++rb)
            #pragma unroll
            for (int r = 0; r < 4; ++r) {
                int rl = wnb + rb * 16 + lq * 4 + r;
                v2s[half * 128 + rl] = bv[rb * 4 + r];
                i2s[half * 128 + rl] = bc[rb * 4 + r];
            }
    }
    __syncthreads();
    if (t < 128) {
        float va = v2s[t], vb = v2s[128 + t];
        int   ia = i2s[t], ib = i2s[128 + t];
        bool useB = vb > va;
        pmax[(size_t)blockIdx.y * NP + n0 + t] = useB ? vb : va;
        pidx[(size_t)blockIdx.y * NP + n0 + t] = useB ? ib : ia;
    }
}

// ---------------- Kernel 3: reduce 72 tile partials -> nn_idx -------------
__global__ __launch_bounds__(256) void kred(
    const float* __restrict__ pmax, const int* __restrict__ pidx,
    int* __restrict__ nn)
{
    __shared__ float cv[4][64];
    __shared__ int   ci[4][64];

    const int t = threadIdx.x;
    const int n = blockIdx.x * 64 + (t & 63);
    const int p = t >> 6;

    float b = -INFINITY;
    int bi = 0x7fffffff;
    #pragma unroll 6
    for (int c = p * 18; c < p * 18 + 18; ++c) {
        float v = pmax[(size_t)c * NP + n];
        int  id = pidx[(size_t)c * NP + n];
        if (v > b || (v == b && id < bi)) { b = v; bi = id; }
    }
    cv[p][t & 63] = b;
    ci[p][t & 63] = bi;
    __syncthreads();
    if (t < 64) {
        b = cv[0][t]; bi = ci[0][t];
        #pragma unroll
        for (int q = 1; q < 4; ++q) {
            float v = cv[q][t]; int id = ci[q][t];
            if (v > b || (v == b && id < bi)) { b = v; bi = id; }
        }
        nn[blockIdx.x * 64 + t] = bi;
    }
}

// ---------------- Kernel 4: gather Y_sel + fused MSE loss ----------------
// y = H*2^-8 + L*2^-19 (<=6e-8 from exact fp32). k-major plane layout.
__global__ __launch_bounds__(256) void kgather(
    const unsigned short* __restrict__ YH, const unsigned short* __restrict__ YL,
    const int* __restrict__ nn,
    const float* __restrict__ Xf, float* __restrict__ Ysel,
    float* __restrict__ lacc)
{
    __shared__ float tile[64][65];
    __shared__ int   idxs[64];
    __shared__ float wsum[4];

    const int n0 = blockIdx.x * 64;
    const int d0 = blockIdx.y * 64;
    const int tid = threadIdx.x;

    if (tid < 64) idxs[tid] = nn[n0 + tid];
    __syncthreads();

    const int c  = tid & 63;
    const int r0 = tid >> 6;

    #pragma unroll
    for (int s = 0; s < 16; ++s) {
        int r = s * 4 + r0;
        int d = d0 + c;
        size_t off = (size_t)(d >> 5) * KCH + (size_t)idxs[r] * 32 + (d & 31);
        tile[r][c] = h2f(YH[off]) * (1.0f / 256.0f)
                   + h2f(YL[off]) * (1.0f / 524288.0f);   // 2^-19
    }
    __syncthreads();

    float lsum = 0.0f;
    #pragma unroll
    for (int s = 0; s < 16; ++s) {
        int a = s * 4 + r0;
        int d = d0 + a;
        int n = n0 + c;
        float y = tile[c][a];          // stride-65: conflict-free
        float x = Xf[(size_t)d * NP + n];
        float diff = x - y;
        lsum = fmaf(diff, diff, lsum);
        Ysel[(size_t)d * NP + n] = y;  // coalesced over n
    }

    #pragma unroll
    for (int off = 32; off >= 1; off >>= 1)
        lsum += __shfl_xor(lsum, off, 64);
    if ((tid & 63) == 0) wsum[tid >> 6] = lsum;
    __syncthreads();
    if (tid == 0)
        atomicAdd(lacc, wsum[0] + wsum[1] + wsum[2] + wsum[3]);
}

// ---------------- Kernel 5: finalize loss ----------------
__global__ void kfin(const float* __restrict__ lacc, float* __restrict__ out)
{
    out[0] = lacc[0] * (1.0f / (float)DN);
}

extern "C" void kernel_launch(void* const* d_in, const int* in_sizes, int n_in,
                              void* d_out, int out_size, void* d_ws, size_t ws_size,
                              hipStream_t stream)
{
    const float* X = (const float*)d_in[0];   // X_features [1,256,96,96]
    const float* Y = (const float*)d_in[1];   // Y_features [1,256,96,96]
    // d_in[2], d_in[3] (images) are dead code in the reference — unused.

    float* out = (float*)d_out;
    float* Ysel_out = out + 1;          // output 1: Y_sel [1,D,N]
    float* Xf_out   = out + 1 + DN;     // output 2: Xf   [1,D,N]  (exact fp32)

    // Workspace (~24.3 MB)
    unsigned short* XH = (unsigned short*)d_ws;   // DN halves each
    unsigned short* XL = XH + DN;
    unsigned short* YH = XL + DN;
    unsigned short* YL = YH + DN;
    float* pmax = (float*)(YL + DN);                // NT*NP
    int*   pidx = (int*)(pmax + (size_t)NT * NP);   // NT*NP
    int*   nn   = pidx + (size_t)NT * NP;           // NP
    float* lacc = (float*)(nn + NP);                // 1

    hipLaunchKernelGGL(kprep, dim3(NP / 64, 2), dim3(256), 0, stream,
                       X, Y, Xf_out, XH, XL, YH, YL, lacc);
    hipLaunchKernelGGL(ksim, dim3(NT, NT), dim3(256), 0, stream,
                       XH, XL, YH, YL, pmax, pidx);
    hipLaunchKernelGGL(kred, dim3(NP / 64), dim3(256), 0, stream,
                       pmax, pidx, nn);
    hipLaunchKernelGGL(kgather, dim3(NP / 64, DC / 64), dim3(256), 0, stream,
                       YH, YL, nn, Xf_out, Ysel_out, lacc);
    hipLaunchKernelGGL(kfin, dim3(1), dim3(1), 0, stream, lacc, out);
}

// Round 10
// 268.242 us; speedup vs baseline: 1.1627x; 1.1627x over previous
//
#include <hip/hip_runtime.h>
#include <math.h>

// Problem constants (B=1 fixed by reference)
#define NP 9216          // S*S spatial positions
#define DC 256           // channels
#define DN (DC * NP)
#define NT 72            // 9216 / 128 tiles per dim
#define KCH (NP * 32)    // halves per k-chunk section of a plane

#define FEPS 2.220446049250313e-16f

typedef __attribute__((ext_vector_type(8))) _Float16 half8v;
typedef __attribute__((ext_vector_type(4))) float   float4v;

union HU { _Float16 h; unsigned short u; };
__device__ __forceinline__ unsigned short f2h(float f) { HU x; x.h = (_Float16)f; return x.u; }
__device__ __forceinline__ float h2f(unsigned short s) { HU x; x.u = s; return (float)x.h; }

// Plane layout (k-major): half index off(n,k) = (k>>5)*KCH + n*32 + (k&31)
// -> one MFMA fragment load (16 positions x 64B) is 1KB contiguous,
// perfectly coalesced global_load_dwordx4. ksim runs with no LDS staging
// and no barriers in the K-loop.

// ---------------- Kernel 1: fused normalize + fp16 split ----------------
// Split: H = fp16(v*2^8); L = fp16((v*2^8 - H)*2^11) (exact residual).
__global__ __launch_bounds__(256) void kprep(
    const float* __restrict__ X, const float* __restrict__ Y,
    float* __restrict__ Xf_out,
    unsigned short* __restrict__ XH, unsigned short* __restrict__ XL,
    unsigned short* __restrict__ YH, unsigned short* __restrict__ YL,
    float* __restrict__ lacc)
{
    __shared__ float tile[64 * 257];   // (n, d) at n*257+d
    __shared__ float psum[4][64];
    __shared__ float invs[64];

    const int t = threadIdx.x;
    const bool isX = (blockIdx.y == 0);
    const float* src = isX ? X : Y;
    unsigned* hT = (unsigned*)(isX ? XH : YH);
    unsigned* lT = (unsigned*)(isX ? XL : YL);
    const int n0 = blockIdx.x * 64;

    if (blockIdx.x == 0 && blockIdx.y == 0 && t == 0) *lacc = 0.0f;

    const int lane = t & 63;
    const int w    = t >> 6;      // wave id -> owns d-range [w*64, w*64+64)

    #pragma unroll 8
    for (int i = 0; i < 64; ++i) {
        int d = w * 64 + i;
        tile[lane * 257 + d] = src[(size_t)d * NP + n0 + lane];
    }
    float s = 0.0f;
    #pragma unroll 8
    for (int i = 0; i < 64; ++i) {
        float v = tile[lane * 257 + w * 64 + i];
        s = fmaf(v, v, s);
    }
    psum[w][lane] = s;
    __syncthreads();
    if (t < 64) {
        float tot = psum[0][t] + psum[1][t] + psum[2][t] + psum[3][t];
        invs[t] = 1.0f / (sqrtf(tot) + FEPS);
    }
    __syncthreads();

    // plane writes, k-major layout; coalesced uints.
    for (int kt = 0; kt < 8; ++kt) {
        #pragma unroll
        for (int p = 0; p < 4; ++p) {
            int idx = p * 256 + t;
            int n = idx >> 4;          // 0..63
            int u = idx & 15;          // uint within chunk (2 halves)
            float inv = invs[n];
            int d = kt * 32 + 2 * u;
            float v0 = tile[n * 257 + d] * inv;
            float v1 = tile[n * 257 + d + 1] * inv;
            float s0 = v0 * 256.0f, s1 = v1 * 256.0f;
            unsigned short h0 = f2h(s0), h1 = f2h(s1);
            unsigned short l0 = f2h((s0 - h2f(h0)) * 2048.0f);
            unsigned short l1 = f2h((s1 - h2f(h1)) * 2048.0f);
            size_t uo = (size_t)kt * (NP * 16) + (size_t)(n0 + n) * 16 + u;
            hT[uo] = (unsigned)h0 | ((unsigned)h1 << 16);
            lT[uo] = (unsigned)l0 | ((unsigned)l1 << 16);
        }
    }

    // exact fp32 Xf output ([d][n], coalesced over n)
    if (isX) {
        const float inv = invs[lane];
        #pragma unroll 8
        for (int i = 0; i < 64; ++i) {
            int d = w * 64 + i;
            Xf_out[(size_t)d * NP + n0 + lane] = tile[lane * 257 + d] * inv;
        }
    }
}

// ---------------- Kernel 2: MFMA sim-GEMM + fused per-row argmax ----------
// Barrier-free K-loop, fragments direct from global (k-major layout),
// compiler-scheduled (R9 showed hand-pipelining loses to occupancy).
// R10: XCD-aware locality swizzle. HW dispatch is round-robin (xcd =
// lid % 8); remap so each XCD owns one contiguous 18x36-tile region,
// traversed in 6x6 sub-squares -> concurrently-active blocks per XCD sit
// in a small patch whose A/B rows (~3 MB) fit the 4 MB per-XCD L2.
// Without this, every XCD streams ~the whole 18.9 MB plane set from L3
// (R8: 2.65 GB / 191 us = 13.9 TB/s = L3-bound).
// sim*2^16 = Hx·Hy + 2^-11(Hx·Ly + Lx·Hy).
__global__ __launch_bounds__(256, 3) void ksim(
    const unsigned short* __restrict__ XH, const unsigned short* __restrict__ XL,
    const unsigned short* __restrict__ YH, const unsigned short* __restrict__ YL,
    float* __restrict__ pmax, int* __restrict__ pidx)
{
    __shared__ float v2s[256];
    __shared__ int   i2s[256];

    const int t = threadIdx.x;

    // ---- block swizzle: lid -> (tx,ty) tile coords ----
    const int lid = blockIdx.y * NT + blockIdx.x;
    const int xcd = lid & 7;
    const int r   = lid >> 3;              // 0..647 within region
    const int sq  = r / 36;                // 6x6 sub-square index (0..17)
    const int wi  = r - sq * 36;           // 0..35 within sub-square
    const int qx  = sq % 3, qy = sq / 3;   // 3x6 grid of sub-squares
    const int sx  = wi % 6,  sy = wi / 6;
    const int tx  = (xcd & 3) * 18 + qx * 6 + sx;   // 0..71
    const int ty  = (xcd >> 2) * 36 + qy * 6 + sy;  // 0..71

    const int n0 = tx * 128;
    const int m0 = ty * 128;

    const int L   = t & 63;
    const int wid = t >> 6;
    const int wnb = (wid >> 1) * 64;   // wave n-offset
    const int wmb = (wid & 1) * 64;    // wave m-offset (col half)
    const int lc  = L & 15;
    const int lq  = L >> 4;

    // fragment base pointers (halves); rb/cb via inst offsets (<=13-bit imm)
    const unsigned short* pAh = XH + (size_t)(n0 + wnb + lc) * 32 + lq * 8;
    const unsigned short* pAl = XL + (size_t)(n0 + wnb + lc) * 32 + lq * 8;
    const unsigned short* pBh = YH + (size_t)(m0 + wmb + lc) * 32 + lq * 8;
    const unsigned short* pBl = YL + (size_t)(m0 + wmb + lc) * 32 + lq * 8;

    float4v acc[4][4];
    #pragma unroll
    for (int i = 0; i < 4; ++i)
        #pragma unroll
        for (int j = 0; j < 4; ++j)
            acc[i][j] = (float4v){0.f, 0.f, 0.f, 0.f};
    const float4v z4 = (float4v){0.f, 0.f, 0.f, 0.f};
    const float CS = 1.0f / 2048.0f;

    #pragma unroll 1
    for (int kt = 0; kt < 8; ++kt) {
        half8v Ah[4], Al[4], Bh[4], Bl[4];
        #pragma unroll
        for (int i = 0; i < 4; ++i) {
            Ah[i] = *(const half8v*)(pAh + i * 512);
            Al[i] = *(const half8v*)(pAl + i * 512);
            Bh[i] = *(const half8v*)(pBh + i * 512);
            Bl[i] = *(const half8v*)(pBl + i * 512);
        }
        #pragma unroll
        for (int cb = 0; cb < 4; ++cb)
            #pragma unroll
            for (int rb = 0; rb < 4; ++rb) {
                float4v tv;
                tv = __builtin_amdgcn_mfma_f32_16x16x32_f16(Al[rb], Bh[cb], z4, 0, 0, 0);
                tv = __builtin_amdgcn_mfma_f32_16x16x32_f16(Ah[rb], Bl[cb], tv, 0, 0, 0);
                acc[rb][cb] = __builtin_amdgcn_mfma_f32_16x16x32_f16(Ah[rb], Bh[cb], acc[rb][cb], 0, 0, 0);
                acc[rb][cb].x = fmaf(tv.x, CS, acc[rb][cb].x);
                acc[rb][cb].y = fmaf(tv.y, CS, acc[rb][cb].y);
                acc[rb][cb].z = fmaf(tv.z, CS, acc[rb][cb].z);
                acc[rb][cb].w = fmaf(tv.w, CS, acc[rb][cb].w);
            }
        pAh += KCH; pAl += KCH; pBh += KCH; pBl += KCH;
    }

    // ---- epilogue: per-row argmax over own col-half ----
    // C/D map: col=lane&15, row=lq*4+reg. Scale 2^16 is argmax-invariant.
    float bv[16]; int bc[16];
    #pragma unroll
    for (int s = 0; s < 16; ++s) { bv[s] = -INFINITY; bc[s] = 0; }

    #pragma unroll
    for (int rb = 0; rb < 4; ++rb)
        #pragma unroll
        for (int cb = 0; cb < 4; ++cb) {   // cb ascending = col ascending
            const int col = m0 + wmb + cb * 16 + lc;
            #pragma unroll
            for (int r2 = 0; r2 < 4; ++r2) {
                float v = acc[rb][cb][r2];
                int s = rb * 4 + r2;
                if (v > bv[s]) { bv[s] = v; bc[s] = col; }
            }
        }

    // reduce across the 16 lc lanes (xor<16 stays in the quad-group)
    #pragma unroll
    for (int off = 1; off < 16; off <<= 1) {
        #pragma unroll
        for (int s = 0; s < 16; ++s) {
            float ov = __shfl_xor(bv[s], off, 64);
            int   oi = __shfl_xor(bc[s], off, 64);
            if (ov > bv[s] || (ov == bv[s] && oi < bc[s])) { bv[s] = ov; bc[s] = oi; }
        }
    }

    // combine the two column-halves via LDS -> one slot per tile.
    // half0 cols < half1 cols: strict '>' keeps half0 on ties (first-max).
    if (lc == 0) {
        const int half = wid & 1;
        #pragma unroll
        for (int rb = 0; rb < 4; ++rb)
            #pragma unroll
            for (int r2 = 0; r2 < 4; ++r2) {
                int rl = wnb + rb * 16 + lq * 4 + r2;
                v2s[half * 128 + rl] = bv[rb * 4 + r2];
                i2s[half * 128 + rl] = bc[rb * 4 + r2];
            }
    }
    __syncthreads();
    if (t < 128) {
        float va = v2s[t], vb = v2s[128 + t];
        int   ia = i2s[t], ib = i2s[128 + t];
        bool useB = vb > va;
        pmax[(size_t)ty * NP + n0 + t] = useB ? vb : va;
        pidx[(size_t)ty * NP + n0 + t] = useB ? ib : ia;
    }
}

// ---------------- Kernel 3: reduce 72 tile partials -> nn_idx -------------
__global__ __launch_bounds__(256) void kred(
    const float* __restrict__ pmax, const int* __restrict__ pidx,
    int* __restrict__ nn)
{
    __shared__ float cv[4][64];
    __shared__ int   ci[4][64];

    const int t = threadIdx.x;
    const int n = blockIdx.x * 64 + (t & 63);
    const int p = t >> 6;

    float b = -INFINITY;
    int bi = 0x7fffffff;
    #pragma unroll 6
    for (int c = p * 18; c < p * 18 + 18; ++c) {
        float v = pmax[(size_t)c * NP + n];
        int  id = pidx[(size_t)c * NP + n];
        if (v > b || (v == b && id < bi)) { b = v; bi = id; }
    }
    cv[p][t & 63] = b;
    ci[p][t & 63] = bi;
    __syncthreads();
    if (t < 64) {
        b = cv[0][t]; bi = ci[0][t];
        #pragma unroll
        for (int q = 1; q < 4; ++q) {
            float v = cv[q][t]; int id = ci[q][t];
            if (v > b || (v == b && id < bi)) { b = v; bi = id; }
        }
        nn[blockIdx.x * 64 + t] = bi;
    }
}

// ---------------- Kernel 4: gather Y_sel + fused MSE loss ----------------
// y = H*2^-8 + L*2^-19 (<=6e-8 from exact fp32). k-major plane layout.
__global__ __launch_bounds__(256) void kgather(
    const unsigned short* __restrict__ YH, const unsigned short* __restrict__ YL,
    const int* __restrict__ nn,
    const float* __restrict__ Xf, float* __restrict__ Ysel,
    float* __restrict__ lacc)
{
    __shared__ float tile[64][65];
    __shared__ int   idxs[64];
    __shared__ float wsum[4];

    const int n0 = blockIdx.x * 64;
    const int d0 = blockIdx.y * 64;
    const int tid = threadIdx.x;

    if (tid < 64) idxs[tid] = nn[n0 + tid];
    __syncthreads();

    const int c  = tid & 63;
    const int r0 = tid >> 6;

    #pragma unroll
    for (int s = 0; s < 16; ++s) {
        int r = s * 4 + r0;
        int d = d0 + c;
        size_t off = (size_t)(d >> 5) * KCH + (size_t)idxs[r] * 32 + (d & 31);
        tile[r][c] = h2f(YH[off]) * (1.0f / 256.0f)
                   + h2f(YL[off]) * (1.0f / 524288.0f);   // 2^-19
    }
    __syncthreads();

    float lsum = 0.0f;
    #pragma unroll
    for (int s = 0; s < 16; ++s) {
        int a = s * 4 + r0;
        int d = d0 + a;
        int n = n0 + c;
        float y = tile[c][a];          // stride-65: conflict-free
        float x = Xf[(size_t)d * NP + n];
        float diff = x - y;
        lsum = fmaf(diff, diff, lsum);
        Ysel[(size_t)d * NP + n] = y;  // coalesced over n
    }

    #pragma unroll
    for (int off = 32; off >= 1; off >>= 1)
        lsum += __shfl_xor(lsum, off, 64);
    if ((tid & 63) == 0) wsum[tid >> 6] = lsum;
    __syncthreads();
    if (tid == 0)
        atomicAdd(lacc, wsum[0] + wsum[1] + wsum[2] + wsum[3]);
}

// ---------------- Kernel 5: finalize loss ----------------
__global__ void kfin(const float* __restrict__ lacc, float* __restrict__ out)
{
    out[0] = lacc[0] * (1.0f / (float)DN);
}

extern "C" void kernel_launch(void* const* d_in, const int* in_sizes, int n_in,
                              void* d_out, int out_size, void* d_ws, size_t ws_size,
                              hipStream_t stream)
{
    const float* X = (const float*)d_in[0];   // X_features [1,256,96,96]
    const float* Y = (const float*)d_in[1];   // Y_features [1,256,96,96]
    // d_in[2], d_in[3] (images) are dead code in the reference — unused.

    float* out = (float*)d_out;
    float* Ysel_out = out + 1;          // output 1: Y_sel [1,D,N]
    float* Xf_out   = out + 1 + DN;     // output 2: Xf   [1,D,N]  (exact fp32)

    // Workspace (~24.3 MB)
    unsigned short* XH = (unsigned short*)d_ws;   // DN halves each
    unsigned short* XL = XH + DN;
    unsigned short* YH = XL + DN;
    unsigned short* YL = YH + DN;
    float* pmax = (float*)(YL + DN);                // NT*NP
    int*   pidx = (int*)(pmax + (size_t)NT * NP);   // NT*NP
    int*   nn   = pidx + (size_t)NT * NP;           // NP
    float* lacc = (float*)(nn + NP);                // 1

    hipLaunchKernelGGL(kprep, dim3(NP / 64, 2), dim3(256), 0, stream,
                       X, Y, Xf_out, XH, XL, YH, YL, lacc);
    hipLaunchKernelGGL(ksim, dim3(NT, NT), dim3(256), 0, stream,
                       XH, XL, YH, YL, pmax, pidx);
    hipLaunchKernelGGL(kred, dim3(NP / 64), dim3(256), 0, stream,
                       pmax, pidx, nn);
    hipLaunchKernelGGL(kgather, dim3(NP / 64, DC / 64), dim3(256), 0, stream,
                       YH, YL, nn, Xf_out, Ysel_out, lacc);
    hipLaunchKernelGGL(kfin, dim3(1), dim3(1), 0, stream, lacc, out);
}